// Round 2
// baseline (600.372 us; speedup 1.0000x reference)
//
#include <hip/hip_runtime.h>

typedef __attribute__((ext_vector_type(8))) short bf16x8;
typedef __attribute__((ext_vector_type(8))) unsigned short u16x8;
typedef __attribute__((ext_vector_type(4))) float f32x4;
typedef unsigned short u16t;

#define MFMA16(a, b, c) __builtin_amdgcn_mfma_f32_16x16x32_bf16((a), (b), (c), 0, 0, 0)
#define GLDS16(gp, lp)                                                        \
  __builtin_amdgcn_global_load_lds(                                           \
      (__attribute__((address_space(1))) void*)(gp),                          \
      (__attribute__((address_space(3))) void*)(lp), 16, 0, 0)

static constexpr float L2E = 1.44269504f;   // log2(e)
static constexpr float MASKV = -1.0e30f;    // finite mask sentinel (no inf paths)
static constexpr float MASKTH = -5.0e29f;   // "is real score" threshold

__device__ __forceinline__ u16t f2b(float f) {
  unsigned u = __builtin_bit_cast(unsigned, f);
  u = u + 0x7fffu + ((u >> 16) & 1u); // RNE
  return (u16t)(u >> 16);
}

// ---------------------------------------------------------------------------
// fp32 -> bf16 conversion of x and the 4 weight matrices, one fused launch.
// ---------------------------------------------------------------------------
__global__ void cvt5(const float* __restrict__ x, const float* __restrict__ wq,
                     const float* __restrict__ wk, const float* __restrict__ wv,
                     const float* __restrict__ wo, u16t* __restrict__ xb,
                     u16t* __restrict__ wqb, u16t* __restrict__ wkb,
                     u16t* __restrict__ wvb, u16t* __restrict__ wob) {
  const int bid = blockIdx.x;
  const float* src; u16t* dst; int gb;
  if (bid < 4096)      { src = x;  dst = xb;  gb = bid; }
  else if (bid < 4608) { src = wq; dst = wqb; gb = bid - 4096; }
  else if (bid < 5120) { src = wk; dst = wkb; gb = bid - 4608; }
  else if (bid < 5632) { src = wv; dst = wvb; gb = bid - 5120; }
  else                 { src = wo; dst = wob; gb = bid - 5632; }
  const size_t i = (size_t)gb * 256 + threadIdx.x; // 8-elem group index
  const float4 a = ((const float4*)src)[2 * i];
  const float4 b = ((const float4*)src)[2 * i + 1];
  u16x8 r;
  r[0] = f2b(a.x); r[1] = f2b(a.y); r[2] = f2b(a.z); r[3] = f2b(a.w);
  r[4] = f2b(b.x); r[5] = f2b(b.y); r[6] = f2b(b.z); r[7] = f2b(b.w);
  *(u16x8*)&dst[8 * i] = r;
}

// ---------------------------------------------------------------------------
// GEMM core (m97 structure): unchanged (passed at 385.7 us).
// ---------------------------------------------------------------------------
__global__ void gemm_qkv(const u16t* __restrict__ X,
                         const u16t* __restrict__ Wq, const u16t* __restrict__ Wk,
                         const u16t* __restrict__ Wv,
                         const float* __restrict__ bq, const float* __restrict__ bk,
                         const float* __restrict__ bv,
                         u16t* __restrict__ Qo, u16t* __restrict__ Ko,
                         u16t* __restrict__ Vo) {
  __shared__ __align__(16) u16t As[128 * 32];
  __shared__ __align__(16) u16t Bs[128 * 32];
  const int t = threadIdx.x, lane = t & 63, w = t >> 6;
  const int wr = w >> 1, wc = w & 1, m = lane & 15, quad = lane >> 4;
  const int rowBase = blockIdx.y * 128, colBase = blockIdx.x * 128;
  const int z = blockIdx.z;
  const u16t* W = (z == 0) ? Wq : ((z == 1) ? Wk : Wv);
  const float* bias = (z == 0) ? bq : ((z == 1) ? bk : bv);
  u16t* Out = (z == 0) ? Qo : ((z == 1) ? Ko : Vo);

  f32x4 acc[4][4];
#pragma unroll
  for (int i = 0; i < 4; i++)
#pragma unroll
    for (int j = 0; j < 4; j++) acc[i][j] = (f32x4){0.f, 0.f, 0.f, 0.f};

  const int lr = lane >> 2, lc = (lane & 3) * 8;
  for (int kt = 0; kt < 32; ++kt) {
#pragma unroll
    for (int i = 0; i < 2; ++i) {
      const int r0 = i * 64 + w * 16;
      GLDS16(&X[(size_t)(rowBase + r0 + lr) * 1024 + kt * 32 + lc], &As[r0 * 32]);
      GLDS16(&W[(size_t)(colBase + r0 + lr) * 1024 + kt * 32 + lc], &Bs[r0 * 32]);
    }
    __syncthreads();
    bf16x8 af[4], bfr[4];
#pragma unroll
    for (int i = 0; i < 4; i++)
      af[i] = *(const bf16x8*)&As[(wr * 64 + i * 16 + m) * 32 + quad * 8];
#pragma unroll
    for (int j = 0; j < 4; j++)
      bfr[j] = *(const bf16x8*)&Bs[(wc * 64 + j * 16 + m) * 32 + quad * 8];
#pragma unroll
    for (int i = 0; i < 4; i++)
#pragma unroll
      for (int j = 0; j < 4; j++) acc[i][j] = MFMA16(af[i], bfr[j], acc[i][j]);
    __syncthreads();
  }

#pragma unroll
  for (int j = 0; j < 4; j++) {
    const int col = colBase + wc * 64 + j * 16 + m;
    const float bv_ = bias[col];
    const int h = col >> 6, hd = col & 63;
#pragma unroll
    for (int i = 0; i < 4; i++) {
#pragma unroll
      for (int r = 0; r < 4; r++) {
        const int row = rowBase + wr * 64 + i * 16 + quad * 4 + r;
        const int b_ = row >> 10, s_ = row & 1023;
        const size_t oi = (((size_t)b_ * 16 + h) * 1024 + s_) * 64 + hd;
        Out[oi] = f2b(acc[i][j][r] + bv_);
      }
    }
  }
}

__global__ void gemm_o(const u16t* __restrict__ A, const u16t* __restrict__ W,
                       const float* __restrict__ bias, float* __restrict__ Out) {
  __shared__ __align__(16) u16t As[128 * 32];
  __shared__ __align__(16) u16t Bs[128 * 32];
  const int t = threadIdx.x, lane = t & 63, w = t >> 6;
  const int wr = w >> 1, wc = w & 1, m = lane & 15, quad = lane >> 4;
  const int rowBase = blockIdx.y * 128, colBase = blockIdx.x * 128;

  f32x4 acc[4][4];
#pragma unroll
  for (int i = 0; i < 4; i++)
#pragma unroll
    for (int j = 0; j < 4; j++) acc[i][j] = (f32x4){0.f, 0.f, 0.f, 0.f};

  const int lr = lane >> 2, lc = (lane & 3) * 8;
  for (int kt = 0; kt < 32; ++kt) {
#pragma unroll
    for (int i = 0; i < 2; ++i) {
      const int r0 = i * 64 + w * 16;
      GLDS16(&A[(size_t)(rowBase + r0 + lr) * 1024 + kt * 32 + lc], &As[r0 * 32]);
      GLDS16(&W[(size_t)(colBase + r0 + lr) * 1024 + kt * 32 + lc], &Bs[r0 * 32]);
    }
    __syncthreads();
    bf16x8 af[4], bfr[4];
#pragma unroll
    for (int i = 0; i < 4; i++)
      af[i] = *(const bf16x8*)&As[(wr * 64 + i * 16 + m) * 32 + quad * 8];
#pragma unroll
    for (int j = 0; j < 4; j++)
      bfr[j] = *(const bf16x8*)&Bs[(wc * 64 + j * 16 + m) * 32 + quad * 8];
#pragma unroll
    for (int i = 0; i < 4; i++)
#pragma unroll
      for (int j = 0; j < 4; j++) acc[i][j] = MFMA16(af[i], bfr[j], acc[i][j]);
    __syncthreads();
  }

#pragma unroll
  for (int j = 0; j < 4; j++) {
    const int col = colBase + wc * 64 + j * 16 + m;
    const float bv_ = bias[col];
#pragma unroll
    for (int i = 0; i < 4; i++) {
#pragma unroll
      for (int r = 0; r < 4; r++) {
        const int row = rowBase + wr * 64 + i * 16 + quad * 4 + r;
        Out[(size_t)row * 1024 + col] = acc[i][j][r] + bv_;
      }
    }
  }
}

// ---------------------------------------------------------------------------
// Flash attention v3: grid (S/128, H, B), 256 thr, 4 waves x 32 q-rows
// (2 sub-tiles of 16). K 64-key tiles: global_load_lds with XOR-granule
// pre-swizzled global source (involution g' = g ^ (row&7)), double-buffered,
// prefetched one tile ahead inside the compute phase. V: global->reg
// (prefetched one tile ahead) then conflict-free swizzled scalar scatter to
// V^T layout: elem [key][hd] at Vt[hd*64 + ((key>>3 ^ hd>>3 ^ hd&7)&7)*8
// + (key&7)] -- per store instruction the 8 hd-groups hit 8 disjoint 4-bank
// windows (2 lanes/bank, free); reads are 16B-aligned ds_read_b128 with the
// inverse XOR. P round-trip via per-wave padded LDS (stride 72).
// ---------------------------------------------------------------------------
__global__ void attn(const u16t* __restrict__ Q, const u16t* __restrict__ K,
                     const u16t* __restrict__ V, const int* __restrict__ ids,
                     u16t* __restrict__ Oo) {
  __shared__ __align__(16) u16t Kb[2][64 * 64];
  __shared__ __align__(16) u16t Vt[64 * 64];
  __shared__ __align__(16) u16t Ps[4][16 * 72];
  __shared__ unsigned long long maskL[16];

  const int t = threadIdx.x, lane = t & 63, w = t >> 6;
  const int m = lane & 15, quad = lane >> 4;
  const int bx = blockIdx.x, h = blockIdx.y, b = blockIdx.z;
  const size_t hoff = ((size_t)b * 16 + h) * 1024 * 64;
  const int qw = bx * 128 + w * 32;     // wave's first q-row
  const int ktmax = 2 * bx + 1;

  // ---- prologue: pad-key bitmask (one u64 per 64-key tile) ----
#pragma unroll
  for (int c = 0; c < 4; ++c) {
    const int chunk = w * 4 + c;
    const int id = ids[b * 1024 + chunk * 64 + lane];
    const unsigned long long mk = __ballot(id != 1);
    if (lane == 0) maskL[chunk] = mk;
  }

  bf16x8 qf[2][2];
#pragma unroll
  for (int mt = 0; mt < 2; ++mt)
#pragma unroll
    for (int hf = 0; hf < 2; ++hf)
      qf[mt][hf] = *(const bf16x8*)&Q[hoff + (size_t)(qw + mt * 16 + m) * 64 +
                                      hf * 32 + quad * 8];

  float mi[2][4], li[2][4];
  f32x4 o[2][4];
#pragma unroll
  for (int mt = 0; mt < 2; ++mt)
#pragma unroll
    for (int r = 0; r < 4; ++r) { mi[mt][r] = MASKV; li[mt][r] = 0.f; }
#pragma unroll
  for (int mt = 0; mt < 2; ++mt)
#pragma unroll
    for (int ot = 0; ot < 4; ++ot) o[mt][ot] = (f32x4){0.f, 0.f, 0.f, 0.f};

  // V-scatter geometry (per thread, tile-independent)
  const int vkey = t >> 3;              // key for it=0 (it=1 adds 32)
  const int vhd0 = (t & 7) * 8;         // first hd of the 8-elem group
  const int vaa = vhd0 >> 3;            // hd group index 0..7

  // K-stage geometry (per thread, tile-independent): 2 GLDS instrs per wave
  const int krow0 = w * 16 + (lane >> 3);            // + s*8
  const int kswz = ((lane & 7) ^ ((lane >> 3) & 7)) * 8;

  // ---- prologue staging: tile 0 ----
  {
#pragma unroll
    for (int s = 0; s < 2; ++s)
      GLDS16(&K[hoff + (size_t)(krow0 + s * 8) * 64 + kswz],
             &Kb[0][(w * 2 + s) * 512]);
  }
  bf16x8 vv0 = *(const bf16x8*)&V[hoff + (size_t)vkey * 64 + vhd0];
  bf16x8 vv1 = *(const bf16x8*)&V[hoff + (size_t)(vkey + 32) * 64 + vhd0];

  u16t* const Pw = &Ps[w][0];

  for (int kt = 0; kt <= ktmax; ++kt) {
    __syncthreads();   // (A): Vt free (prev compute done); tile-kt loads drained
    // scatter V tile kt into swizzled V^T
#pragma unroll
    for (int j = 0; j < 8; ++j) {
      const int hd = vhd0 + j;
      const int g0 = ((vkey >> 3) ^ vaa ^ j) & 7;
      const int g1 = (((vkey >> 3) + 4) ^ vaa ^ j) & 7;
      Vt[hd * 64 + g0 * 8 + (vkey & 7)] = (u16t)vv0[j];
      Vt[hd * 64 + g1 * 8 + (vkey & 7)] = (u16t)vv1[j];
    }
    __syncthreads();   // (B): Vt ready for all waves
    // prefetch tile kt+1 (overlaps compute below; drained at next (A))
    if (kt < ktmax) {
#pragma unroll
      for (int s = 0; s < 2; ++s)
        GLDS16(&K[hoff + (size_t)((kt + 1) * 64 + krow0 + s * 8) * 64 + kswz],
               &Kb[(kt + 1) & 1][(w * 2 + s) * 512]);
      vv0 = *(const bf16x8*)&V[hoff + (size_t)((kt + 1) * 64 + vkey) * 64 + vhd0];
      vv1 = *(const bf16x8*)&V[hoff + (size_t)((kt + 1) * 64 + vkey + 32) * 64 + vhd0];
    }

    const u16t* Kc = Kb[kt & 1];
    const unsigned long long km = maskL[kt];

#pragma unroll
    for (int mt = 0; mt < 2; ++mt) {
      if ((kt * 64) <= (qw + mt * 16 + 15)) {      // wave-uniform causal skip
        const int qr0 = qw + mt * 16 + quad * 4;   // + r = q row
        // ---- scores: Q @ K^T over 4 key sub-tiles ----
        f32x4 sc[4];
        float rowmax[4] = {MASKV, MASKV, MASKV, MASKV};
#pragma unroll
        for (int nt = 0; nt < 4; ++nt) {
          if ((kt * 64 + nt * 16) <= (qw + mt * 16 + 15)) {
            const bf16x8 k0 =
                *(const bf16x8*)&Kc[(nt * 16 + m) * 64 + ((quad ^ (m & 7)) * 8)];
            const bf16x8 k1 =
                *(const bf16x8*)&Kc[(nt * 16 + m) * 64 + (((quad + 4) ^ (m & 7)) * 8)];
            f32x4 c = (f32x4){0.f, 0.f, 0.f, 0.f};
            c = MFMA16(qf[mt][0], k0, c);
            c = MFMA16(qf[mt][1], k1, c);
            const int key = kt * 64 + nt * 16 + m;
            const bool pv = ((km >> (nt * 16 + m)) & 1ull) != 0;
#pragma unroll
            for (int r = 0; r < 4; ++r) {
              const float s = (pv && key <= qr0 + r) ? c[r] * 0.125f : MASKV;
              sc[nt][r] = s;
              rowmax[r] = fmaxf(rowmax[r], s);
            }
          } else {
#pragma unroll
            for (int r = 0; r < 4; ++r) sc[nt][r] = MASKV;
          }
        }
        // ---- online softmax ----
#pragma unroll
        for (int r = 0; r < 4; ++r) {
          float v_ = rowmax[r];
          v_ = fmaxf(v_, __shfl_xor(v_, 1));
          v_ = fmaxf(v_, __shfl_xor(v_, 2));
          v_ = fmaxf(v_, __shfl_xor(v_, 4));
          v_ = fmaxf(v_, __shfl_xor(v_, 8));
          rowmax[r] = v_;
        }
        float alpha[4], rsum[4];
#pragma unroll
        for (int r = 0; r < 4; ++r) {
          const float mn = fmaxf(mi[mt][r], rowmax[r]);
          alpha[r] = exp2f((mi[mt][r] - mn) * L2E);
          mi[mt][r] = mn;
          rsum[r] = 0.f;
        }
#pragma unroll
        for (int nt = 0; nt < 4; ++nt)
#pragma unroll
          for (int r = 0; r < 4; ++r) {
            const float p =
                (sc[nt][r] > MASKTH) ? exp2f((sc[nt][r] - mi[mt][r]) * L2E) : 0.f;
            rsum[r] += p;
            Pw[(quad * 4 + r) * 72 + nt * 16 + m] = f2b(p);
          }
#pragma unroll
        for (int r = 0; r < 4; ++r) {
          float v_ = rsum[r];
          v_ += __shfl_xor(v_, 1);
          v_ += __shfl_xor(v_, 2);
          v_ += __shfl_xor(v_, 4);
          v_ += __shfl_xor(v_, 8);
          li[mt][r] = li[mt][r] * alpha[r] + v_;
        }
#pragma unroll
        for (int ot = 0; ot < 4; ++ot)
#pragma unroll
          for (int r = 0; r < 4; ++r) o[mt][ot][r] *= alpha[r];

        // ---- P @ V ----
        const bf16x8 pf0 = *(const bf16x8*)&Pw[m * 72 + quad * 8];
        const bf16x8 pf1 = *(const bf16x8*)&Pw[m * 72 + 32 + quad * 8];
#pragma unroll
        for (int ot = 0; ot < 4; ++ot) {
          const int hd = ot * 16 + m;
          const int sz = (ot * 2 + (m >> 3)) ^ (m & 7);   // hd>>3 ^ hd&7
          const bf16x8 v0 = *(const bf16x8*)&Vt[hd * 64 + ((quad ^ sz) & 7) * 8];
          const bf16x8 v1 = *(const bf16x8*)&Vt[hd * 64 + (((quad + 4) ^ sz) & 7) * 8];
          o[mt][ot] = MFMA16(pf0, v0, o[mt][ot]);
          o[mt][ot] = MFMA16(pf1, v1, o[mt][ot]);
        }
      }
    }
  }

  // ---- epilogue: write attn output [B,S,D] with D-index = h*64 + hd ----
#pragma unroll
  for (int mt = 0; mt < 2; ++mt)
#pragma unroll
    for (int r = 0; r < 4; ++r) {
      const float inv = li[mt][r] > 1e-30f ? 1.f / li[mt][r] : 0.f;
      const int q = qw + mt * 16 + quad * 4 + r;
#pragma unroll
      for (int ot = 0; ot < 4; ++ot) {
        const int col = h * 64 + ot * 16 + m;
        Oo[((size_t)(b * 1024 + q)) * 1024 + col] = f2b(o[mt][ot][r] * inv);
      }
    }
}

// ---------------------------------------------------------------------------
extern "C" void kernel_launch(void* const* d_in, const int* in_sizes, int n_in,
                              void* d_out, int out_size, void* d_ws, size_t ws_size,
                              hipStream_t stream) {
  const float* x  = (const float*)d_in[0];
  const int*   ids = (const int*)d_in[1];
  const float* Wq = (const float*)d_in[2];
  const float* bq = (const float*)d_in[3];
  const float* Wk = (const float*)d_in[4];
  const float* bk = (const float*)d_in[5];
  const float* Wv = (const float*)d_in[6];
  const float* bv = (const float*)d_in[7];
  const float* Wo = (const float*)d_in[8];
  const float* bo = (const float*)d_in[9];
  float* out = (float*)d_out;

  // ws layout (bf16 elems): XB 8.4M | WqB,WkB,WvB,WoB 1M each | Q,K,V 8.4M each
  u16t* XB  = (u16t*)d_ws;
  u16t* WqB = XB  + 8388608;
  u16t* WkB = WqB + 1048576;
  u16t* WvB = WkB + 1048576;
  u16t* WoB = WvB + 1048576;
  u16t* Qw  = WoB + 1048576;
  u16t* Kw  = Qw  + 8388608;
  u16t* Vw  = Kw  + 8388608;
  u16t* AO  = XB; // reuse after gemm_qkv consumed XB

  cvt5<<<6144, 256, 0, stream>>>(x, Wq, Wk, Wv, Wo, XB, WqB, WkB, WvB, WoB);
  gemm_qkv<<<dim3(8, 64, 3), 256, 0, stream>>>(XB, WqB, WkB, WvB, bq, bk, bv,
                                               Qw, Kw, Vw);
  attn<<<dim3(8, 16, 8), 256, 0, stream>>>(Qw, Kw, Vw, ids, AO);
  gemm_o<<<dim3(8, 64, 1), 256, 0, stream>>>(AO, WoB, bo, out);
}

// Round 3
// 417.714 us; speedup vs baseline: 1.4373x; 1.4373x over previous
//
#include <hip/hip_runtime.h>

typedef __attribute__((ext_vector_type(8))) short bf16x8;
typedef __attribute__((ext_vector_type(8))) unsigned short u16x8;
typedef __attribute__((ext_vector_type(4))) float f32x4;
typedef unsigned short u16t;

#define MFMA16(a, b, c) __builtin_amdgcn_mfma_f32_16x16x32_bf16((a), (b), (c), 0, 0, 0)
#define GLDS16(gp, lp)                                                        \
  __builtin_amdgcn_global_load_lds(                                           \
      (__attribute__((address_space(1))) void*)(gp),                          \
      (__attribute__((address_space(3))) void*)(lp), 16, 0, 0)

static constexpr float L2E = 1.44269504f;   // log2(e)
static constexpr float MASKV = -1.0e30f;    // finite mask sentinel (no inf paths)
static constexpr float MASKTH = -5.0e29f;   // "is real score" threshold

__device__ __forceinline__ u16t f2b(float f) {
  unsigned u = __builtin_bit_cast(unsigned, f);
  u = u + 0x7fffu + ((u >> 16) & 1u); // RNE
  return (u16t)(u >> 16);
}

// ---------------------------------------------------------------------------
// fp32 -> bf16 conversion of x and the 4 weight matrices, one fused launch.
// ---------------------------------------------------------------------------
__global__ void cvt5(const float* __restrict__ x, const float* __restrict__ wq,
                     const float* __restrict__ wk, const float* __restrict__ wv,
                     const float* __restrict__ wo, u16t* __restrict__ xb,
                     u16t* __restrict__ wqb, u16t* __restrict__ wkb,
                     u16t* __restrict__ wvb, u16t* __restrict__ wob) {
  const int bid = blockIdx.x;
  const float* src; u16t* dst; int gb;
  if (bid < 4096)      { src = x;  dst = xb;  gb = bid; }
  else if (bid < 4608) { src = wq; dst = wqb; gb = bid - 4096; }
  else if (bid < 5120) { src = wk; dst = wkb; gb = bid - 4608; }
  else if (bid < 5632) { src = wv; dst = wvb; gb = bid - 5120; }
  else                 { src = wo; dst = wob; gb = bid - 5632; }
  const size_t i = (size_t)gb * 256 + threadIdx.x; // 8-elem group index
  const float4 a = ((const float4*)src)[2 * i];
  const float4 b = ((const float4*)src)[2 * i + 1];
  u16x8 r;
  r[0] = f2b(a.x); r[1] = f2b(a.y); r[2] = f2b(a.z); r[3] = f2b(a.w);
  r[4] = f2b(b.x); r[5] = f2b(b.y); r[6] = f2b(b.z); r[7] = f2b(b.w);
  *(u16x8*)&dst[8 * i] = r;
}

// ---------------------------------------------------------------------------
// GEMM core (m97 structure): unchanged (passed at 385.7 us).
// ---------------------------------------------------------------------------
__global__ void gemm_qkv(const u16t* __restrict__ X,
                         const u16t* __restrict__ Wq, const u16t* __restrict__ Wk,
                         const u16t* __restrict__ Wv,
                         const float* __restrict__ bq, const float* __restrict__ bk,
                         const float* __restrict__ bv,
                         u16t* __restrict__ Qo, u16t* __restrict__ Ko,
                         u16t* __restrict__ Vo) {
  __shared__ __align__(16) u16t As[128 * 32];
  __shared__ __align__(16) u16t Bs[128 * 32];
  const int t = threadIdx.x, lane = t & 63, w = t >> 6;
  const int wr = w >> 1, wc = w & 1, m = lane & 15, quad = lane >> 4;
  const int rowBase = blockIdx.y * 128, colBase = blockIdx.x * 128;
  const int z = blockIdx.z;
  const u16t* W = (z == 0) ? Wq : ((z == 1) ? Wk : Wv);
  const float* bias = (z == 0) ? bq : ((z == 1) ? bk : bv);
  u16t* Out = (z == 0) ? Qo : ((z == 1) ? Ko : Vo);

  f32x4 acc[4][4];
#pragma unroll
  for (int i = 0; i < 4; i++)
#pragma unroll
    for (int j = 0; j < 4; j++) acc[i][j] = (f32x4){0.f, 0.f, 0.f, 0.f};

  const int lr = lane >> 2, lc = (lane & 3) * 8;
  for (int kt = 0; kt < 32; ++kt) {
#pragma unroll
    for (int i = 0; i < 2; ++i) {
      const int r0 = i * 64 + w * 16;
      GLDS16(&X[(size_t)(rowBase + r0 + lr) * 1024 + kt * 32 + lc], &As[r0 * 32]);
      GLDS16(&W[(size_t)(colBase + r0 + lr) * 1024 + kt * 32 + lc], &Bs[r0 * 32]);
    }
    __syncthreads();
    bf16x8 af[4], bfr[4];
#pragma unroll
    for (int i = 0; i < 4; i++)
      af[i] = *(const bf16x8*)&As[(wr * 64 + i * 16 + m) * 32 + quad * 8];
#pragma unroll
    for (int j = 0; j < 4; j++)
      bfr[j] = *(const bf16x8*)&Bs[(wc * 64 + j * 16 + m) * 32 + quad * 8];
#pragma unroll
    for (int i = 0; i < 4; i++)
#pragma unroll
      for (int j = 0; j < 4; j++) acc[i][j] = MFMA16(af[i], bfr[j], acc[i][j]);
    __syncthreads();
  }

#pragma unroll
  for (int j = 0; j < 4; j++) {
    const int col = colBase + wc * 64 + j * 16 + m;
    const float bv_ = bias[col];
    const int h = col >> 6, hd = col & 63;
#pragma unroll
    for (int i = 0; i < 4; i++) {
#pragma unroll
      for (int r = 0; r < 4; r++) {
        const int row = rowBase + wr * 64 + i * 16 + quad * 4 + r;
        const int b_ = row >> 10, s_ = row & 1023;
        const size_t oi = (((size_t)b_ * 16 + h) * 1024 + s_) * 64 + hd;
        Out[oi] = f2b(acc[i][j][r] + bv_);
      }
    }
  }
}

__global__ void gemm_o(const u16t* __restrict__ A, const u16t* __restrict__ W,
                       const float* __restrict__ bias, float* __restrict__ Out) {
  __shared__ __align__(16) u16t As[128 * 32];
  __shared__ __align__(16) u16t Bs[128 * 32];
  const int t = threadIdx.x, lane = t & 63, w = t >> 6;
  const int wr = w >> 1, wc = w & 1, m = lane & 15, quad = lane >> 4;
  const int rowBase = blockIdx.y * 128, colBase = blockIdx.x * 128;

  f32x4 acc[4][4];
#pragma unroll
  for (int i = 0; i < 4; i++)
#pragma unroll
    for (int j = 0; j < 4; j++) acc[i][j] = (f32x4){0.f, 0.f, 0.f, 0.f};

  const int lr = lane >> 2, lc = (lane & 3) * 8;
  for (int kt = 0; kt < 32; ++kt) {
#pragma unroll
    for (int i = 0; i < 2; ++i) {
      const int r0 = i * 64 + w * 16;
      GLDS16(&A[(size_t)(rowBase + r0 + lr) * 1024 + kt * 32 + lc], &As[r0 * 32]);
      GLDS16(&W[(size_t)(colBase + r0 + lr) * 1024 + kt * 32 + lc], &Bs[r0 * 32]);
    }
    __syncthreads();
    bf16x8 af[4], bfr[4];
#pragma unroll
    for (int i = 0; i < 4; i++)
      af[i] = *(const bf16x8*)&As[(wr * 64 + i * 16 + m) * 32 + quad * 8];
#pragma unroll
    for (int j = 0; j < 4; j++)
      bfr[j] = *(const bf16x8*)&Bs[(wc * 64 + j * 16 + m) * 32 + quad * 8];
#pragma unroll
    for (int i = 0; i < 4; i++)
#pragma unroll
      for (int j = 0; j < 4; j++) acc[i][j] = MFMA16(af[i], bfr[j], acc[i][j]);
    __syncthreads();
  }

#pragma unroll
  for (int j = 0; j < 4; j++) {
    const int col = colBase + wc * 64 + j * 16 + m;
    const float bv_ = bias[col];
#pragma unroll
    for (int i = 0; i < 4; i++) {
#pragma unroll
      for (int r = 0; r < 4; r++) {
        const int row = rowBase + wr * 64 + i * 16 + quad * 4 + r;
        Out[(size_t)row * 1024 + col] = acc[i][j][r] + bv_;
      }
    }
  }
}

// ---------------------------------------------------------------------------
// Flash attention v4: v0 geometry (grid (16,16,8), 4 waves x 16 q-rows, K
// direct from global -> L2-shared across the 16 blocks per (b,h)) with three
// surgical changes:
//  1. K fragments register-prefetched one tile ahead (no exposed global
//     latency before the QK MFMAs).
//  2. V register-prefetched one tile ahead; scatter to V^T is conflict-free:
//     V[key][hd] stored at Vt[hd*72 + ((key&7) | (((key>>3)^(hd>>3))&7)<<3)].
//     Per store instruction the 8 hd-groups hit 8 distinct 4-bank windows
//     (2 lanes/bank = free; old layout was 16-way). Reads are 16B-aligned
//     b128 with granule quad^((hd>>3)&7) -- same involution.
//  3. Vt double-buffered -> ONE __syncthreads per tile (reader drains lgkm
//     at the barrier; writer targets the other buffer; skew <= 1 phase).
// ---------------------------------------------------------------------------
__global__ void attn(const u16t* __restrict__ Q, const u16t* __restrict__ K,
                     const u16t* __restrict__ V, const int* __restrict__ ids,
                     u16t* __restrict__ Oo) {
  constexpr int PSTR = 72;
  __shared__ __align__(16) u16t Vt[2][64 * PSTR];
  __shared__ __align__(16) u16t Ps[4][16 * PSTR];
  __shared__ unsigned long long maskL[16];

  const int t = threadIdx.x, lane = t & 63, w = t >> 6;
  const int m = lane & 15, quad = lane >> 4;
  const int qt = blockIdx.x, h = blockIdx.y, b = blockIdx.z;
  const size_t hoff = ((size_t)b * 16 + h) * 1024 * 64;
  const int qbase = qt * 64 + w * 16;
  const int qrow0 = qbase + quad * 4; // + r

  // ---- pad-key bitmask (one u64 per 64-key tile) ----
#pragma unroll
  for (int c = 0; c < 4; ++c) {
    const int chunk = w * 4 + c;
    const int id = ids[b * 1024 + chunk * 64 + lane];
    const unsigned long long mk = __ballot(id != 1);
    if (lane == 0) maskL[chunk] = mk;
  }

  const bf16x8 qf0 = *(const bf16x8*)&Q[hoff + (size_t)(qbase + m) * 64 + quad * 8];
  const bf16x8 qf1 = *(const bf16x8*)&Q[hoff + (size_t)(qbase + m) * 64 + 32 + quad * 8];

  float mi[4], li[4];
  f32x4 o[4];
#pragma unroll
  for (int r = 0; r < 4; r++) { mi[r] = MASKV; li[r] = 0.f; }
#pragma unroll
  for (int ot = 0; ot < 4; ot++) o[ot] = (f32x4){0.f, 0.f, 0.f, 0.f};

  // V-scatter geometry (per thread, tile-independent)
  const int vkey = t >> 3;          // key 0..31 (it=1 adds 32)
  const int a0 = t & 7;             // hd group: rows a0*8 .. a0*8+7
  const int sk0 = (vkey & 7) | ((((vkey >> 3) ^ a0) & 7) << 3);
  const int sk1 = (vkey & 7) | (((((vkey >> 3) + 4) ^ a0) & 7) << 3);

  // ---- tile-0 register prefetch: K fragments + V rows ----
  bf16x8 kf0[4], kf1[4];
#pragma unroll
  for (int nt = 0; nt < 4; ++nt) {
    kf0[nt] = *(const bf16x8*)&K[hoff + (size_t)(nt * 16 + m) * 64 + quad * 8];
    kf1[nt] = *(const bf16x8*)&K[hoff + (size_t)(nt * 16 + m) * 64 + 32 + quad * 8];
  }
  bf16x8 vv0 = *(const bf16x8*)&V[hoff + (size_t)vkey * 64 + a0 * 8];
  bf16x8 vv1 = *(const bf16x8*)&V[hoff + (size_t)(vkey + 32) * 64 + a0 * 8];

  u16t* const Pw = &Ps[w][0];

  for (int kt = 0; kt <= qt; ++kt) {
    // ---- scatter V tile kt into swizzled V^T (conflict-free) ----
    u16t* const vb = &Vt[kt & 1][0];
#pragma unroll
    for (int j = 0; j < 8; ++j) {
      vb[(a0 * 8 + j) * PSTR + sk0] = (u16t)vv0[j];
      vb[(a0 * 8 + j) * PSTR + sk1] = (u16t)vv1[j];
    }
    __syncthreads();   // Vt[kt&1] ready; prior-buffer readers drained

    const unsigned long long km = maskL[kt];

    // ---- scores: Q @ K^T over 4 key sub-tiles (K already in regs) ----
    f32x4 sc[4];
    float rowmax[4] = {MASKV, MASKV, MASKV, MASKV};
#pragma unroll
    for (int nt = 0; nt < 4; nt++) {
      const bool active = (kt * 64 + nt * 16) <= (qbase + 15); // wave-uniform
      if (active) {
        f32x4 c = (f32x4){0.f, 0.f, 0.f, 0.f};
        c = MFMA16(qf0, kf0[nt], c);
        c = MFMA16(qf1, kf1[nt], c);
        const int key = kt * 64 + nt * 16 + m;
        const bool pv = ((km >> (nt * 16 + m)) & 1ull) != 0;
#pragma unroll
        for (int r = 0; r < 4; r++) {
          const float s = (pv && key <= qrow0 + r) ? c[r] * 0.125f : MASKV;
          sc[nt][r] = s;
          rowmax[r] = fmaxf(rowmax[r], s);
        }
      } else {
#pragma unroll
        for (int r = 0; r < 4; r++) sc[nt][r] = MASKV;
      }
    }

    // ---- register prefetch for tile kt+1 (latency hidden under softmax+PV) --
    if (kt < qt) {
#pragma unroll
      for (int nt = 0; nt < 4; ++nt) {
        kf0[nt] = *(const bf16x8*)&K[hoff +
                  (size_t)((kt + 1) * 64 + nt * 16 + m) * 64 + quad * 8];
        kf1[nt] = *(const bf16x8*)&K[hoff +
                  (size_t)((kt + 1) * 64 + nt * 16 + m) * 64 + 32 + quad * 8];
      }
      vv0 = *(const bf16x8*)&V[hoff + (size_t)((kt + 1) * 64 + vkey) * 64 + a0 * 8];
      vv1 = *(const bf16x8*)&V[hoff + (size_t)((kt + 1) * 64 + vkey + 32) * 64 + a0 * 8];
    }

    // ---- online softmax ----
#pragma unroll
    for (int r = 0; r < 4; r++) {
      float v_ = rowmax[r];
      v_ = fmaxf(v_, __shfl_xor(v_, 1));
      v_ = fmaxf(v_, __shfl_xor(v_, 2));
      v_ = fmaxf(v_, __shfl_xor(v_, 4));
      v_ = fmaxf(v_, __shfl_xor(v_, 8));
      rowmax[r] = v_;
    }
    float alpha[4], rsum[4];
#pragma unroll
    for (int r = 0; r < 4; r++) {
      const float mn = fmaxf(mi[r], rowmax[r]);
      alpha[r] = exp2f((mi[r] - mn) * L2E); // finite arg; underflows to 0
      mi[r] = mn;
      rsum[r] = 0.f;
    }
#pragma unroll
    for (int nt = 0; nt < 4; nt++) {
#pragma unroll
      for (int r = 0; r < 4; r++) {
        const float p =
            (sc[nt][r] > MASKTH) ? exp2f((sc[nt][r] - mi[r]) * L2E) : 0.f;
        rsum[r] += p;
        Pw[(quad * 4 + r) * PSTR + nt * 16 + m] = f2b(p);
      }
    }
#pragma unroll
    for (int r = 0; r < 4; r++) {
      float v_ = rsum[r];
      v_ += __shfl_xor(v_, 1);
      v_ += __shfl_xor(v_, 2);
      v_ += __shfl_xor(v_, 4);
      v_ += __shfl_xor(v_, 8);
      li[r] = li[r] * alpha[r] + v_;
    }
#pragma unroll
    for (int ot = 0; ot < 4; ot++)
#pragma unroll
      for (int r = 0; r < 4; r++) o[ot][r] *= alpha[r];

    // ---- P @ V (V via swizzled b128 reads) ----
    const bf16x8 p0 = *(const bf16x8*)&Pw[m * PSTR + quad * 8];
    const bf16x8 p1 = *(const bf16x8*)&Pw[m * PSTR + 32 + quad * 8];
#pragma unroll
    for (int ot = 0; ot < 4; ot++) {
      const int hd = ot * 16 + m;
      const int ra = (ot * 2 + (m >> 3)) & 7;           // (hd>>3)&7
      const bf16x8 v0 = *(const bf16x8*)&vb[hd * PSTR + ((quad ^ ra) & 7) * 8];
      const bf16x8 v1 = *(const bf16x8*)&vb[hd * PSTR + (((quad + 4) ^ ra) & 7) * 8];
      o[ot] = MFMA16(p0, v0, o[ot]);
      o[ot] = MFMA16(p1, v1, o[ot]);
    }
  }

  // ---- write attn output [B,S,D] with D-index = h*64 + hd (bf16, ws) ----
#pragma unroll
  for (int r = 0; r < 4; r++) {
    const float inv = li[r] > 1e-30f ? 1.f / li[r] : 0.f;
    const int q = qbase + quad * 4 + r;
#pragma unroll
    for (int ot = 0; ot < 4; ot++) {
      const int col = h * 64 + ot * 16 + m;
      Oo[((size_t)(b * 1024 + q)) * 1024 + col] = f2b(o[ot][r] * inv);
    }
  }
}

// ---------------------------------------------------------------------------
extern "C" void kernel_launch(void* const* d_in, const int* in_sizes, int n_in,
                              void* d_out, int out_size, void* d_ws, size_t ws_size,
                              hipStream_t stream) {
  const float* x  = (const float*)d_in[0];
  const int*   ids = (const int*)d_in[1];
  const float* Wq = (const float*)d_in[2];
  const float* bq = (const float*)d_in[3];
  const float* Wk = (const float*)d_in[4];
  const float* bk = (const float*)d_in[5];
  const float* Wv = (const float*)d_in[6];
  const float* bv = (const float*)d_in[7];
  const float* Wo = (const float*)d_in[8];
  const float* bo = (const float*)d_in[9];
  float* out = (float*)d_out;

  // ws layout (bf16 elems): XB 8.4M | WqB,WkB,WvB,WoB 1M each | Q,K,V 8.4M each
  u16t* XB  = (u16t*)d_ws;
  u16t* WqB = XB  + 8388608;
  u16t* WkB = WqB + 1048576;
  u16t* WvB = WkB + 1048576;
  u16t* WoB = WvB + 1048576;
  u16t* Qw  = WoB + 1048576;
  u16t* Kw  = Qw  + 8388608;
  u16t* Vw  = Kw  + 8388608;
  u16t* AO  = XB; // reuse after gemm_qkv consumed XB

  cvt5<<<6144, 256, 0, stream>>>(x, Wq, Wk, Wv, Wo, XB, WqB, WkB, WvB, WoB);
  gemm_qkv<<<dim3(8, 64, 3), 256, 0, stream>>>(XB, WqB, WkB, WvB, bq, bk, bv,
                                               Qw, Kw, Vw);
  attn<<<dim3(16, 16, 8), 256, 0, stream>>>(Qw, Kw, Vw, ids, AO);
  gemm_o<<<dim3(8, 64, 1), 256, 0, stream>>>(AO, WoB, bo, out);
}